// Round 6
// baseline (2082.053 us; speedup 1.0000x reference)
//
#include <hip/hip_runtime.h>
#include <hip/hip_bf16.h>
#include <stdint.h>

// Problem dims (fixed by the reference setup_inputs):
//   a_previous [8192, 4096] f32, theta [4096, 4098] f32, aging [4096, 4098] f32
//   out [8192, 4096] f32
#define M_DIM 8192
#define N_DIM 4096
#define K_IN  4096          // n_in
#define NC    (K_IN + 2)    // 4098 theta/aging columns
#define K_DIM (2 * K_IN)    // GEMM K: [a | inv(a)] concatenated, i8 elems (= bytes)

#define BM 256
#define BN 256
#define BKB 64              // K-bytes per tile (i8) -> 64 B rows, 64 KiB LDS total
#define NT (K_DIM / BKB)    // 128 K-tiles

typedef __attribute__((ext_vector_type(4))) int i32x4;   // i8 MFMA A/B frag + acc

__device__ __forceinline__ float fast_tanh(float y) {
  float e = __expf(2.0f * y);
  return 1.0f - 2.0f * __builtin_amdgcn_rcpf(1.0f + e);
}

__device__ __forceinline__ int q8(float x) {   // round-to-nearest, fits i8 by range
  return (int)__builtin_rintf(x);
}

// ---------------------------------------------------------------------------
// prep_A: A' = [i8(a*127) | i8(inv(a)*127)], shape [8192][8192] i8
// ---------------------------------------------------------------------------
__global__ __launch_bounds__(256) void prep_A(const float* __restrict__ a,
                                              int8_t* __restrict__ Ap) {
  int idx = blockIdx.x * 256 + threadIdx.x;       // one float4 per thread
  int j  = idx >> 10;
  int k4 = (idx & 1023) << 2;
  float4 v = reinterpret_cast<const float4*>(a)[idx];
  float xs[4] = {v.x, v.y, v.z, v.w};
  int lw = 0, rw = 0;
#pragma unroll
  for (int t = 0; t < 4; ++t) {
    float x = xs[t];
    int ql = q8(x * 127.0f);
    float inv = 0.104f - 0.899f * fast_tanh((x + 0.056f) * 3.858f);
    int qr = q8(inv * 127.0f);
    lw |= (ql & 255) << (8 * t);
    rw |= (qr & 255) << (8 * t);
  }
  size_t base = (size_t)j * K_DIM + k4;
  *reinterpret_cast<int*>(Ap + base)        = lw;   // a half
  *reinterpret_cast<int*>(Ap + base + K_IN) = rw;   // inv(a) half
}

// ---------------------------------------------------------------------------
// prep_B: th = st(theta*aging); W = |th|/rowsum; per-row q8 with scale
// 127/max|th_ingemm|; B' = [qWp | qWn] i8; corr[i] f32 exact; sc[i] dequant.
// ---------------------------------------------------------------------------
__global__ __launch_bounds__(256) void prep_B(const float* __restrict__ theta,
                                              const float* __restrict__ aging,
                                              int8_t* __restrict__ Bp,
                                              float* __restrict__ corr,
                                              float* __restrict__ sc) {
  __shared__ float th_s[NC];
  __shared__ float red_s[256];
  __shared__ float red_m[256];
  int i = blockIdx.x;
  int tid = threadIdx.x;
  const float* tr = theta + (size_t)i * NC;
  const float* ar = aging + (size_t)i * NC;
  float psum = 0.f, pmax = 0.f;
  for (int k = tid; k < NC; k += 256) {
    float th = tr[k] * ar[k];
    if (fabsf(th) < 0.01f) th = 0.f;
    th_s[k] = th;
    psum += fabsf(th);
    if (k < K_IN) pmax = fmaxf(pmax, fabsf(th));
  }
  red_s[tid] = psum;
  red_m[tid] = pmax;
  __syncthreads();
  for (int s = 128; s > 0; s >>= 1) {
    if (tid < s) {
      red_s[tid] += red_s[tid + s];
      red_m[tid] = fmaxf(red_m[tid], red_m[tid + s]);
    }
    __syncthreads();
  }
  float inv_sum = 1.0f / red_s[0];
  float maxabs  = red_m[0];
  float qs = 127.0f / maxabs;
  int8_t* out = Bp + (size_t)i * K_DIM;
  for (int k0 = tid * 4; k0 < K_IN; k0 += 1024) {
    int pw = 0, nw = 0;
#pragma unroll
    for (int t = 0; t < 4; ++t) {
      float th = th_s[k0 + t];
      int q = q8(fabsf(th) * qs);
      if (th >= 0.f) pw |= (q & 255) << (8 * t);
      else           nw |= (q & 255) << (8 * t);
    }
    *reinterpret_cast<int*>(out + k0)         = pw;   // Wp (pairs with a)
    *reinterpret_cast<int*>(out + K_IN + k0)  = nw;   // Wn (pairs with inv(a))
  }
  if (tid == 0) {
    float th1 = th_s[K_IN];
    float th2 = th_s[K_IN + 1];
    float w1 = fabsf(th1) * inv_sum;
    float w2 = fabsf(th2) * inv_sum;
    float inv1 = 0.104f - 0.899f * fast_tanh((1.0f + 0.056f) * 3.858f);
    float inv0 = 0.104f - 0.899f * fast_tanh((0.0f + 0.056f) * 3.858f);
    float c = (th1 >= 0.f) ? w1 : w1 * inv1;
    c += (th2 >= 0.f) ? 0.0f : w2 * inv0;
    corr[i] = c;
    sc[i] = maxabs * inv_sum * (1.0f / 16129.0f);   // 1/(127*127)
  }
}

// ---------------------------------------------------------------------------
// gemm_fused (i8): 256x256 tile, BKB=64, 8 waves (2Mx4N), 2 phases/K-tile,
// one barrier per phase. LDS = 2buf x (A 16KB + B 16KB) = 64 KiB -> 2 blocks
// per CU (4 waves/SIMD) for cross-block MFMA/LDS overlap.
// Swizzle (64B rows, 4 x16B slots): byte slot ^= ((row>>1)&3)<<4 on both
// sides (involution pair, rule 21); 8 bank-groups x 2-way = conflict-free.
// Per K-tile W: ph0 {read A m0-3 + B n0-3 (8); stage ALL of tile W+1 (4 glds);
// barrier; lgkm0; MFMA q0 x16}; ph1 {read A m4-7 (4); vmcnt(0); barrier;
// lgkm0; MFMA q1 x16}. vmcnt(0) at ph1 guarantees tile W+1 fully landed
// before W+1 ph0's reads (issued right after ph1's MFMA, pre-barrier).
// Region ledger: stages at W ph0 write buf[(W+1)&1]; its last reads were
// W-1 ph0 (A0-3,B) / W-1 ph1 (A4-7) -> one barrier + MFMA cluster margin.
// ---------------------------------------------------------------------------
__global__ __launch_bounds__(512, 4) void gemm_fused(const int8_t* __restrict__ A,
                                                     const int8_t* __restrict__ B,
                                                     const float* __restrict__ corr,
                                                     const float* __restrict__ sc,
                                                     float* __restrict__ C) {
  extern __shared__ char lds[];   // 65536 B
  const int tid  = threadIdx.x;
  const int lane = tid & 63;
  const int wid  = tid >> 6;     // 0..7
  const int wr   = wid >> 2;     // 0..1  -> M offset wr*128
  const int wc   = wid & 3;      // 0..3  -> N offset wc*64
  const int fr   = lane & 15;

  // T1: XCD-aware swizzle; nwg = 512, divisible by 8 -> bijective
  const int bid = (int)blockIdx.x;
  const int sw  = (bid & 7) * 64 + (bid >> 3);
  const int bm0 = (sw >> 4) * BM;     // 32 M-blocks
  const int bn0 = (sw & 15) * BN;     // 16 N-blocks

  // staging: linear LDS dest (glds), per-lane GLOBAL source col pre-swizzled.
  // thread -> (row = tid>>2, slot = tid&3); source slot = slot ^ ((row>>1)&3)
  const int colsw = (((tid & 3) ^ ((tid >> 3) & 3)) << 4);
  const int8_t* gA = A + (size_t)(bm0 + (tid >> 2)) * K_DIM + colsw;
  const int8_t* gB = B + (size_t)(bn0 + (tid >> 2)) * K_DIM + colsw;
  const int dst_t = tid * 16;

  // read-side swizzled fragment byte offsets (within a 64B row)
  const int flip = ((fr >> 1) & 3) << 4;
  const int cs   = ((lane >> 4) * 16) ^ flip;
  const int aRow = (wr * 128 + fr) * BKB;              // byte offset of frag row
  const int bRow = (wc * 64 + fr) * BKB;

  i32x4 acc[8][4] = {};

  // stage matrix (ISA=1 -> A) for K-tile T: 2 x glds x16B (rows 0-127, 128-255)
#define STAGE(ISA, T) do {                                                           \
    const int8_t* _g = (ISA) ? gA : gB;                                              \
    const size_t _go = (size_t)(T) * BKB;                                            \
    char* _l = lds + (((T) & 1) * 32768) + ((ISA) ? 0 : 16384) + dst_t;              \
    __builtin_amdgcn_global_load_lds(                                                \
        (const __attribute__((address_space(1))) unsigned int*)(_g + _go),           \
        (__attribute__((address_space(3))) unsigned int*)_l, 16, 0, 0);              \
    __builtin_amdgcn_global_load_lds(                                                \
        (const __attribute__((address_space(1))) unsigned int*)(_g + _go + (size_t)128 * K_DIM), \
        (__attribute__((address_space(3))) unsigned int*)(_l + 8192), 16, 0, 0);     \
  } while (0)

#define MFMA(a, b, c) __builtin_amdgcn_mfma_i32_16x16x64_i8((a), (b), (c), 0, 0, 0)

  // ---- prologue: stage tile0 (4 glds); drain; barrier
  STAGE(0, 0); STAGE(1, 0);
  asm volatile("s_waitcnt vmcnt(0)" ::: "memory");
  __builtin_amdgcn_s_barrier();

#pragma unroll 2
  for (int W = 0; W < NT; ++W) {
    const char* pa = lds + (W & 1) * 32768 + aRow;
    const char* pb = lds + (W & 1) * 32768 + 16384 + bRow;
    i32x4 af[8], bf[4];

    // ===== phase 0: read A m0-3 (4) + B n0-3 (4); stage tile W+1 (4 glds)
#pragma unroll
    for (int m = 0; m < 4; ++m)
      af[m] = *(const i32x4*)(pa + m * 16 * BKB + cs);
#pragma unroll
    for (int n = 0; n < 4; ++n)
      bf[n] = *(const i32x4*)(pb + n * 16 * BKB + cs);
    if (W + 1 < NT) { STAGE(0, W + 1); STAGE(1, W + 1); }
    __builtin_amdgcn_s_barrier();
    asm volatile("s_waitcnt lgkmcnt(0)" ::: "memory");
    __builtin_amdgcn_sched_barrier(0);
    __builtin_amdgcn_s_setprio(1);
#pragma unroll
    for (int m = 0; m < 4; ++m)
#pragma unroll
      for (int n = 0; n < 4; ++n)
        acc[m][n] = MFMA(af[m], bf[n], acc[m][n]);
    __builtin_amdgcn_s_setprio(0);

    // ===== phase 1: read A m4-7 (4); vmcnt(0) -> tile W+1 landed; MFMA q1
#pragma unroll
    for (int m = 4; m < 8; ++m)
      af[m] = *(const i32x4*)(pa + m * 16 * BKB + cs);
    asm volatile("s_waitcnt vmcnt(0)" ::: "memory");
    __builtin_amdgcn_s_barrier();
    asm volatile("s_waitcnt lgkmcnt(0)" ::: "memory");
    __builtin_amdgcn_sched_barrier(0);
    __builtin_amdgcn_s_setprio(1);
#pragma unroll
    for (int m = 4; m < 8; ++m)
#pragma unroll
      for (int n = 0; n < 4; ++n)
        acc[m][n] = MFMA(af[m], bf[n], acc[m][n]);
    __builtin_amdgcn_s_setprio(0);
  }

  // ---- epilogue: z = acc*sc[n] + corr[n]; activation; store
  const int rb = (lane >> 4) * 4;
#pragma unroll
  for (int n = 0; n < 4; ++n) {
    const int col = bn0 + wc * 64 + n * 16 + fr;
    const float cr = corr[col];
    const float s  = sc[col];
#pragma unroll
    for (int mi = 0; mi < 8; ++mi) {
      const int row0 = bm0 + wr * 128 + mi * 16 + rb;
#pragma unroll
      for (int j = 0; j < 4; ++j) {
        float z = (float)acc[mi][n][j] * s + cr;
        float e = __expf((z - 0.183f) * 48.2f);
        C[(size_t)(row0 + j) * N_DIM + col] = 1.096f - 1.924f * __builtin_amdgcn_rcpf(1.0f + e);
      }
    }
  }
#undef STAGE
#undef MFMA
}

// ---------------------------------------------------------------------------
extern "C" void kernel_launch(void* const* d_in, const int* in_sizes, int n_in,
                              void* d_out, int out_size, void* d_ws, size_t ws_size,
                              hipStream_t stream) {
  (void)in_sizes; (void)n_in; (void)out_size; (void)ws_size;
  const float* a_prev = (const float*)d_in[0];
  const float* theta  = (const float*)d_in[1];
  const float* aging  = (const float*)d_in[2];
  float* out = (float*)d_out;

  char* ws = (char*)d_ws;
  int8_t* Ap = (int8_t*)ws;                                        // 67.1 MB
  int8_t* Bp = (int8_t*)(ws + (size_t)M_DIM * K_DIM);              // 33.6 MB
  float* corr = (float*)(ws + (size_t)M_DIM * K_DIM + (size_t)N_DIM * K_DIM);
  float* sc   = corr + N_DIM;

  prep_A<<<(M_DIM * K_IN / 4) / 256, 256, 0, stream>>>(a_prev, Ap);
  prep_B<<<N_DIM, 256, 0, stream>>>(theta, aging, Bp, corr, sc);

  (void)hipFuncSetAttribute((const void*)gemm_fused,
                            hipFuncAttributeMaxDynamicSharedMemorySize, 65536);
  gemm_fused<<<dim3((M_DIM / BM) * (N_DIM / BN)), dim3(512), 65536, stream>>>(Ap, Bp, corr, sc, out);
}

// Round 7
// 368.932 us; speedup vs baseline: 5.6435x; 5.6435x over previous
//
#include <hip/hip_runtime.h>
#include <hip/hip_bf16.h>
#include <stdint.h>

// Problem dims (fixed by the reference setup_inputs):
//   a_previous [8192, 4096] f32, theta [4096, 4098] f32, aging [4096, 4098] f32
//   out [8192, 4096] f32
#define M_DIM 8192
#define N_DIM 4096
#define K_IN  4096          // n_in
#define NC    (K_IN + 2)    // 4098 theta/aging columns
#define K_DIM (2 * K_IN)    // GEMM K: [a | inv(a)] concatenated, i8 elems (= bytes)

#define BM 256
#define BN 128
#define BKB 64              // K-bytes per tile -> 64B rows
#define NT (K_DIM / BKB)    // 128 K-tiles
#define LDS_BUF 24576       // A 16KB + B 8KB per buffer

typedef __attribute__((ext_vector_type(4))) int i32x4;   // i8 MFMA A/B frag + acc

__device__ __forceinline__ float fast_tanh(float y) {
  float e = __expf(2.0f * y);
  return 1.0f - 2.0f * __builtin_amdgcn_rcpf(1.0f + e);
}

__device__ __forceinline__ int q8(float x) {   // round-to-nearest, fits i8 by range
  return (int)__builtin_rintf(x);
}

// ---------------------------------------------------------------------------
// prep_A: A' = [i8(a*127) | i8(inv(a)*127)], shape [8192][8192] i8
// ---------------------------------------------------------------------------
__global__ __launch_bounds__(256) void prep_A(const float* __restrict__ a,
                                              int8_t* __restrict__ Ap) {
  int idx = blockIdx.x * 256 + threadIdx.x;       // one float4 per thread
  int j  = idx >> 10;
  int k4 = (idx & 1023) << 2;
  float4 v = reinterpret_cast<const float4*>(a)[idx];
  float xs[4] = {v.x, v.y, v.z, v.w};
  int lw = 0, rw = 0;
#pragma unroll
  for (int t = 0; t < 4; ++t) {
    float x = xs[t];
    int ql = q8(x * 127.0f);
    float inv = 0.104f - 0.899f * fast_tanh((x + 0.056f) * 3.858f);
    int qr = q8(inv * 127.0f);
    lw |= (ql & 255) << (8 * t);
    rw |= (qr & 255) << (8 * t);
  }
  size_t base = (size_t)j * K_DIM + k4;
  *reinterpret_cast<int*>(Ap + base)        = lw;   // a half
  *reinterpret_cast<int*>(Ap + base + K_IN) = rw;   // inv(a) half
}

// ---------------------------------------------------------------------------
// prep_B: th = st(theta*aging); W = |th|/rowsum; per-row q8 with scale
// 127/max|th_ingemm|; B' = [qWp | qWn] i8; corr[i] f32 exact; sc[i] dequant.
// ---------------------------------------------------------------------------
__global__ __launch_bounds__(256) void prep_B(const float* __restrict__ theta,
                                              const float* __restrict__ aging,
                                              int8_t* __restrict__ Bp,
                                              float* __restrict__ corr,
                                              float* __restrict__ sc) {
  __shared__ float th_s[NC];
  __shared__ float red_s[256];
  __shared__ float red_m[256];
  int i = blockIdx.x;
  int tid = threadIdx.x;
  const float* tr = theta + (size_t)i * NC;
  const float* ar = aging + (size_t)i * NC;
  float psum = 0.f, pmax = 0.f;
  for (int k = tid; k < NC; k += 256) {
    float th = tr[k] * ar[k];
    if (fabsf(th) < 0.01f) th = 0.f;
    th_s[k] = th;
    psum += fabsf(th);
    if (k < K_IN) pmax = fmaxf(pmax, fabsf(th));
  }
  red_s[tid] = psum;
  red_m[tid] = pmax;
  __syncthreads();
  for (int s = 128; s > 0; s >>= 1) {
    if (tid < s) {
      red_s[tid] += red_s[tid + s];
      red_m[tid] = fmaxf(red_m[tid], red_m[tid + s]);
    }
    __syncthreads();
  }
  float inv_sum = 1.0f / red_s[0];
  float maxabs  = red_m[0];
  float qs = 127.0f / maxabs;
  int8_t* out = Bp + (size_t)i * K_DIM;
  for (int k0 = tid * 4; k0 < K_IN; k0 += 1024) {
    int pw = 0, nw = 0;
#pragma unroll
    for (int t = 0; t < 4; ++t) {
      float th = th_s[k0 + t];
      int q = q8(fabsf(th) * qs);
      if (th >= 0.f) pw |= (q & 255) << (8 * t);
      else           nw |= (q & 255) << (8 * t);
    }
    *reinterpret_cast<int*>(out + k0)         = pw;   // Wp (pairs with a)
    *reinterpret_cast<int*>(out + K_IN + k0)  = nw;   // Wn (pairs with inv(a))
  }
  if (tid == 0) {
    float th1 = th_s[K_IN];
    float th2 = th_s[K_IN + 1];
    float w1 = fabsf(th1) * inv_sum;
    float w2 = fabsf(th2) * inv_sum;
    float inv1 = 0.104f - 0.899f * fast_tanh((1.0f + 0.056f) * 3.858f);
    float inv0 = 0.104f - 0.899f * fast_tanh((0.0f + 0.056f) * 3.858f);
    float c = (th1 >= 0.f) ? w1 : w1 * inv1;
    c += (th2 >= 0.f) ? 0.0f : w2 * inv0;
    corr[i] = c;
    sc[i] = maxabs * inv_sum * (1.0f / 16129.0f);   // 1/(127*127)
  }
}

// ---------------------------------------------------------------------------
// gemm_fused (i8): 256x128 tile, BKB=64, 4 waves (2Mx2N, per-wave 128x64),
// 2 phases/K-tile, one barrier per phase. LDS = 2buf x 24KB = 48 KB ->
// TWO blocks resident per CU (8 waves/CU in two independent barrier groups:
// one block's read/drain phases overlap the other's MFMA clusters).
// __launch_bounds__(256,2) -> VGPR cap 256, no spill (R6 post-mortem: the
// (512,4) bound capped VGPR at 128 -> acc spilled to scratch -> 10 GB HBM).
// Swizzle (64B rows, 4 x16B slots): slot ^= ((row>>1)&3) on both sides
// (involution pair, rule 21) -- correctness-proven in R6 (absmax 0).
// Per K-tile W (buf=W&1): ph0 {read A m0-3 + B n0-3 (8 ds); stage ALL of
// tile W+1 (6 glds) -> buf^1; barrier; lgkm0; MFMA q0 x16}; ph1 {read A m4-7
// (4 ds); vmcnt(0); barrier; lgkm0; MFMA q1 x16}.
// Ledger: buf^1's last reads issue at W-1 ph1 pre-barrier; stages issue at
// W ph0 (after that barrier). Tile W+1 landed before W+1 ph0 reads via ph1's
// vmcnt(0)+barrier. Same ledger as R6 (refcheck-passed).
// ---------------------------------------------------------------------------
__global__ __launch_bounds__(256, 2) void gemm_fused(const int8_t* __restrict__ A,
                                                     const int8_t* __restrict__ B,
                                                     const float* __restrict__ corr,
                                                     const float* __restrict__ sc,
                                                     float* __restrict__ C) {
  extern __shared__ char lds[];   // 49152 B
  const int tid  = threadIdx.x;
  const int lane = tid & 63;
  const int wid  = tid >> 6;     // 0..3
  const int wr   = wid >> 1;     // 0..1  -> M offset wr*128
  const int wc   = wid & 1;      // 0..1  -> N offset wc*64
  const int fr   = lane & 15;

  // T1: XCD-aware swizzle; nwg = 1024, divisible by 8 -> bijective.
  // 32 M-blocks x 32 N-blocks; consecutive sw share the M-panel (A reuse in L2)
  const int bid = (int)blockIdx.x;
  const int sw  = (bid & 7) * 128 + (bid >> 3);
  const int bm0 = (sw >> 5) * BM;     // 32 M-blocks
  const int bn0 = (sw & 31) * BN;     // 32 N-blocks

  // staging: linear LDS dest (glds), per-lane GLOBAL source slot pre-swizzled.
  // thread -> (row = tid>>2 within 64-row group, slot = tid&3)
  const int colsw = (((tid & 3) ^ ((tid >> 3) & 3)) << 4);
  const int8_t* gA = A + (size_t)(bm0 + (tid >> 2)) * K_DIM + colsw;
  const int8_t* gB = B + (size_t)(bn0 + (tid >> 2)) * K_DIM + colsw;
  const int dst_t = tid * 16;

  // read-side swizzled fragment byte offsets (within a 64B row)
  const int flip = ((fr >> 1) & 3) << 4;
  const int cs   = ((lane >> 4) << 4) ^ flip;
  const int aRow = (wr * 128 + fr) * BKB;   // byte offset of frag base row in A region
  const int bRow = (wc * 64 + fr) * BKB;    // ... in B region

  i32x4 acc[8][4] = {};

  // stage K-tile T into buf (T&1): A rows 0..255 (4 x 4KB), B rows 0..127 (2 x 4KB)
#define STAGE(T) do {                                                                \
    char* _lb = lds + ((T) & 1) * LDS_BUF;                                           \
    const size_t _go = (size_t)(T) * BKB;                                            \
    _Pragma("unroll")                                                                \
    for (int _i = 0; _i < 4; ++_i)                                                   \
      __builtin_amdgcn_global_load_lds(                                              \
          (const __attribute__((address_space(1))) unsigned int*)(gA + _go + (size_t)_i * 64 * K_DIM), \
          (__attribute__((address_space(3))) unsigned int*)(_lb + _i * 4096 + dst_t), 16, 0, 0); \
    _Pragma("unroll")                                                                \
    for (int _i = 0; _i < 2; ++_i)                                                   \
      __builtin_amdgcn_global_load_lds(                                              \
          (const __attribute__((address_space(1))) unsigned int*)(gB + _go + (size_t)_i * 64 * K_DIM), \
          (__attribute__((address_space(3))) unsigned int*)(_lb + 16384 + _i * 4096 + dst_t), 16, 0, 0); \
  } while (0)

#define MFMA(a, b, c) __builtin_amdgcn_mfma_i32_16x16x64_i8((a), (b), (c), 0, 0, 0)

  // ---- prologue: stage tile0; drain; barrier
  STAGE(0);
  asm volatile("s_waitcnt vmcnt(0)" ::: "memory");
  __builtin_amdgcn_s_barrier();

#pragma unroll 2
  for (int W = 0; W < NT; ++W) {
    const char* pa = lds + (W & 1) * LDS_BUF + aRow;
    const char* pb = lds + (W & 1) * LDS_BUF + 16384 + bRow;
    i32x4 af[8], bf[4];

    // ===== phase 0: read A m0-3 (4) + B n0-3 (4); stage tile W+1 (6 glds)
#pragma unroll
    for (int m = 0; m < 4; ++m)
      af[m] = *(const i32x4*)(pa + m * 16 * BKB + cs);
#pragma unroll
    for (int n = 0; n < 4; ++n)
      bf[n] = *(const i32x4*)(pb + n * 16 * BKB + cs);
    if (W + 1 < NT) STAGE(W + 1);
    __builtin_amdgcn_s_barrier();
    asm volatile("s_waitcnt lgkmcnt(0)" ::: "memory");
    __builtin_amdgcn_sched_barrier(0);
    __builtin_amdgcn_s_setprio(1);
#pragma unroll
    for (int m = 0; m < 4; ++m)
#pragma unroll
      for (int n = 0; n < 4; ++n)
        acc[m][n] = MFMA(af[m], bf[n], acc[m][n]);
    __builtin_amdgcn_s_setprio(0);

    // ===== phase 1: read A m4-7 (4); vmcnt(0) -> tile W+1 landed; MFMA q1
#pragma unroll
    for (int m = 4; m < 8; ++m)
      af[m] = *(const i32x4*)(pa + m * 16 * BKB + cs);
    asm volatile("s_waitcnt vmcnt(0)" ::: "memory");
    __builtin_amdgcn_s_barrier();
    asm volatile("s_waitcnt lgkmcnt(0)" ::: "memory");
    __builtin_amdgcn_sched_barrier(0);
    __builtin_amdgcn_s_setprio(1);
#pragma unroll
    for (int m = 4; m < 8; ++m)
#pragma unroll
      for (int n = 0; n < 4; ++n)
        acc[m][n] = MFMA(af[m], bf[n], acc[m][n]);
    __builtin_amdgcn_s_setprio(0);
  }

  // ---- epilogue: z = acc*sc[n] + corr[n]; activation; store
  const int rb = (lane >> 4) * 4;
#pragma unroll
  for (int n = 0; n < 4; ++n) {
    const int col = bn0 + wc * 64 + n * 16 + fr;
    const float cr = corr[col];
    const float s  = sc[col];
#pragma unroll
    for (int mi = 0; mi < 8; ++mi) {
      const int row0 = bm0 + wr * 128 + mi * 16 + rb;
#pragma unroll
      for (int j = 0; j < 4; ++j) {
        float z = (float)acc[mi][n][j] * s + cr;
        float e = __expf((z - 0.183f) * 48.2f);
        C[(size_t)(row0 + j) * N_DIM + col] = 1.096f - 1.924f * __builtin_amdgcn_rcpf(1.0f + e);
      }
    }
  }
#undef STAGE
#undef MFMA
}

// ---------------------------------------------------------------------------
extern "C" void kernel_launch(void* const* d_in, const int* in_sizes, int n_in,
                              void* d_out, int out_size, void* d_ws, size_t ws_size,
                              hipStream_t stream) {
  (void)in_sizes; (void)n_in; (void)out_size; (void)ws_size;
  const float* a_prev = (const float*)d_in[0];
  const float* theta  = (const float*)d_in[1];
  const float* aging  = (const float*)d_in[2];
  float* out = (float*)d_out;

  char* ws = (char*)d_ws;
  int8_t* Ap = (int8_t*)ws;                                        // 67.1 MB
  int8_t* Bp = (int8_t*)(ws + (size_t)M_DIM * K_DIM);              // 33.6 MB
  float* corr = (float*)(ws + (size_t)M_DIM * K_DIM + (size_t)N_DIM * K_DIM);
  float* sc   = corr + N_DIM;

  prep_A<<<(M_DIM * K_IN / 4) / 256, 256, 0, stream>>>(a_prev, Ap);
  prep_B<<<N_DIM, 256, 0, stream>>>(theta, aging, Bp, corr, sc);

  (void)hipFuncSetAttribute((const void*)gemm_fused,
                            hipFuncAttributeMaxDynamicSharedMemorySize, 65536);
  gemm_fused<<<dim3((M_DIM / BM) * (N_DIM / BN)), dim3(256), 49152, stream>>>(Ap, Bp, corr, sc, out);
}

// Round 8
// 306.042 us; speedup vs baseline: 6.8032x; 1.2055x over previous
//
#include <hip/hip_runtime.h>
#include <hip/hip_bf16.h>
#include <stdint.h>

// Problem dims (fixed by the reference setup_inputs):
//   a_previous [8192, 4096] f32, theta [4096, 4098] f32, aging [4096, 4098] f32
//   out [8192, 4096] f32
#define M_DIM 8192
#define N_DIM 4096
#define K_IN  4096          // n_in
#define NC    (K_IN + 2)    // 4098 theta/aging columns
#define K_DIM (2 * K_IN)    // GEMM K: [a | inv(a)] concatenated, i8 elems (= bytes)

#define BM 256
#define BN 256
#define BKB 128             // K-bytes per tile (i8) -> 128 B rows (R5 geometry)
#define NT (K_DIM / BKB)    // 64 K-tiles

typedef __attribute__((ext_vector_type(4))) int i32x4;    // 16B A/B fragment
typedef __attribute__((ext_vector_type(16))) int i32x16;  // 32x32 acc

__device__ __forceinline__ float fast_tanh(float y) {
  float e = __expf(2.0f * y);
  return 1.0f - 2.0f * __builtin_amdgcn_rcpf(1.0f + e);
}

__device__ __forceinline__ int q8(float x) {   // round-to-nearest, fits i8 by range
  return (int)__builtin_rintf(x);
}

// ---------------------------------------------------------------------------
// prep_A: A' = [i8(a*127) | i8(inv(a)*127)], shape [8192][8192] i8
// ---------------------------------------------------------------------------
__global__ __launch_bounds__(256) void prep_A(const float* __restrict__ a,
                                              int8_t* __restrict__ Ap) {
  int idx = blockIdx.x * 256 + threadIdx.x;       // one float4 per thread
  int j  = idx >> 10;
  int k4 = (idx & 1023) << 2;
  float4 v = reinterpret_cast<const float4*>(a)[idx];
  float xs[4] = {v.x, v.y, v.z, v.w};
  int lw = 0, rw = 0;
#pragma unroll
  for (int t = 0; t < 4; ++t) {
    float x = xs[t];
    int ql = q8(x * 127.0f);
    float inv = 0.104f - 0.899f * fast_tanh((x + 0.056f) * 3.858f);
    int qr = q8(inv * 127.0f);
    lw |= (ql & 255) << (8 * t);
    rw |= (qr & 255) << (8 * t);
  }
  size_t base = (size_t)j * K_DIM + k4;
  *reinterpret_cast<int*>(Ap + base)        = lw;   // a half
  *reinterpret_cast<int*>(Ap + base + K_IN) = rw;   // inv(a) half
}

// ---------------------------------------------------------------------------
// prep_B: th = st(theta*aging); W = |th|/rowsum; per-row q8 with scale
// 127/max|th_ingemm|; B' = [qWp | qWn] i8; corr[i] f32 exact; sc[i] dequant.
// ---------------------------------------------------------------------------
__global__ __launch_bounds__(256) void prep_B(const float* __restrict__ theta,
                                              const float* __restrict__ aging,
                                              int8_t* __restrict__ Bp,
                                              float* __restrict__ corr,
                                              float* __restrict__ sc) {
  __shared__ float th_s[NC];
  __shared__ float red_s[256];
  __shared__ float red_m[256];
  int i = blockIdx.x;
  int tid = threadIdx.x;
  const float* tr = theta + (size_t)i * NC;
  const float* ar = aging + (size_t)i * NC;
  float psum = 0.f, pmax = 0.f;
  for (int k = tid; k < NC; k += 256) {
    float th = tr[k] * ar[k];
    if (fabsf(th) < 0.01f) th = 0.f;
    th_s[k] = th;
    psum += fabsf(th);
    if (k < K_IN) pmax = fmaxf(pmax, fabsf(th));
  }
  red_s[tid] = psum;
  red_m[tid] = pmax;
  __syncthreads();
  for (int s = 128; s > 0; s >>= 1) {
    if (tid < s) {
      red_s[tid] += red_s[tid + s];
      red_m[tid] = fmaxf(red_m[tid], red_m[tid + s]);
    }
    __syncthreads();
  }
  float inv_sum = 1.0f / red_s[0];
  float maxabs  = red_m[0];
  float qs = 127.0f / maxabs;
  int8_t* out = Bp + (size_t)i * K_DIM;
  for (int k0 = tid * 4; k0 < K_IN; k0 += 1024) {
    int pw = 0, nw = 0;
#pragma unroll
    for (int t = 0; t < 4; ++t) {
      float th = th_s[k0 + t];
      int q = q8(fabsf(th) * qs);
      if (th >= 0.f) pw |= (q & 255) << (8 * t);
      else           nw |= (q & 255) << (8 * t);
    }
    *reinterpret_cast<int*>(out + k0)         = pw;   // Wp (pairs with a)
    *reinterpret_cast<int*>(out + K_IN + k0)  = nw;   // Wn (pairs with inv(a))
  }
  if (tid == 0) {
    float th1 = th_s[K_IN];
    float th2 = th_s[K_IN + 1];
    float w1 = fabsf(th1) * inv_sum;
    float w2 = fabsf(th2) * inv_sum;
    float inv1 = 0.104f - 0.899f * fast_tanh((1.0f + 0.056f) * 3.858f);
    float inv0 = 0.104f - 0.899f * fast_tanh((0.0f + 0.056f) * 3.858f);
    float c = (th1 >= 0.f) ? w1 : w1 * inv1;
    c += (th2 >= 0.f) ? 0.0f : w2 * inv0;
    corr[i] = c;
    sc[i] = maxabs * inv_sum * (1.0f / 16129.0f);   // 1/(127*127)
  }
}

// ---------------------------------------------------------------------------
// gemm_fused (i8, 32x32x32): R5's proven 256x256 / BKB=128 / 8-wave / 4-phase
// one-barrier-per-phase schedule, with mfma_i32_32x32x32_i8 (+12% ceiling,
// half the MFMA instruction count). Per wave: 128x64 out = 4 m-tiles x 2
// n-tiles of 32x32, 4 K-steps of 32 per K-tile -> 32 MFMA/wave/K-tile.
// Fragment mapping: A/B lane holds 16B contiguous K at row/col = lane&31,
// k0 = (lane>>5)*16 + ks*32. C/D: col=lane&31, row=(reg&3)+8*(reg>>2)+
// 4*(lane>>5) [guide m74/m101, dtype-independent].
// Phases (reads / MFMA quadrant):  p0: A m01 (8) + B n0 (4) / m01xn0
//   p1: B n1 (4) / m01xn1    p2: A m23 (8); stage B(W+2) / m23xn0
//   p3: stage A(W+2); vmcnt(8) / m23xn1
// Swizzle + ledger identical to R5 (refcheck-passed, 0 conflicts).
// ---------------------------------------------------------------------------
__global__ __launch_bounds__(512, 2) void gemm_fused(const int8_t* __restrict__ A,
                                                     const int8_t* __restrict__ B,
                                                     const float* __restrict__ corr,
                                                     const float* __restrict__ sc,
                                                     float* __restrict__ C) {
  extern __shared__ char lds[];   // 131072 B
  const int tid  = threadIdx.x;
  const int lane = tid & 63;
  const int wid  = tid >> 6;     // 0..7
  const int wr   = wid >> 2;     // 0..1  -> M offset wr*128
  const int wc   = wid & 3;      // 0..3  -> N offset wc*64
  const int fr   = lane & 31;    // fragment row/col (32-row tiles)
  const int kg   = lane >> 5;    // k-group 0/1 (16B each)

  // T1: XCD-aware swizzle; nwg = 512, divisible by 8 -> bijective
  const int bid = (int)blockIdx.x;
  const int sw  = (bid & 7) * 64 + (bid >> 3);
  const int bm0 = (sw >> 4) * BM;     // 32 M-blocks
  const int bn0 = (sw & 15) * BN;     // 16 N-blocks

  // staging: linear LDS dest (glds), per-lane GLOBAL source col pre-swizzled
  const int colsw = ((tid & 7) * 16) ^ (((tid >> 3) & 7) << 4);   // bytes
  const int8_t* gA = A + (size_t)(bm0 + (tid >> 3)) * K_DIM + colsw;
  const int8_t* gB = B + (size_t)(bn0 + (tid >> 3)) * K_DIM + colsw;
  const int dst_t = tid * 16;

  // read-side swizzled fragment byte offsets (within a 128B row)
  const int flip = (fr & 7) << 4;
  int csk[4];
#pragma unroll
  for (int ks = 0; ks < 4; ++ks) csk[ks] = (ks * 32 + kg * 16) ^ flip;
  const int aRow = (wr * 128 + fr) * BKB;              // byte offset of frag row
  const int bRow = (wc * 64 + fr) * BKB;

  i32x16 acc[4][2] = {};   // [m-tile][n-tile]

#define STAGE(ISA, H, T) do {                                                        \
    const int8_t* _g = (ISA) ? gA : gB;                                              \
    const size_t _go = (size_t)((H) * 128) * K_DIM + (size_t)(T) * BKB;              \
    char* _l = lds + (((T) & 1) * 65536) + ((ISA) ? 0 : 32768) + (H) * 16384 + dst_t; \
    __builtin_amdgcn_global_load_lds(                                                \
        (const __attribute__((address_space(1))) unsigned int*)(_g + _go),           \
        (__attribute__((address_space(3))) unsigned int*)_l, 16, 0, 0);              \
    __builtin_amdgcn_global_load_lds(                                                \
        (const __attribute__((address_space(1))) unsigned int*)(_g + _go + (size_t)64 * K_DIM), \
        (__attribute__((address_space(3))) unsigned int*)(_l + 8192), 16, 0, 0);     \
  } while (0)

#define MFMA32(a, b, c) __builtin_amdgcn_mfma_i32_32x32x32_i8((a), (b), (c), 0, 0, 0)

  // ---- prologue: tile0 + tile1 fully staged (16 loads); wait tile0 (8 left)
  STAGE(0, 0, 0); STAGE(0, 1, 0); STAGE(1, 0, 0); STAGE(1, 1, 0);
  STAGE(0, 0, 1); STAGE(0, 1, 1); STAGE(1, 0, 1); STAGE(1, 1, 1);
  asm volatile("s_waitcnt vmcnt(8)" ::: "memory");
  __builtin_amdgcn_s_barrier();

#pragma unroll 2
  for (int W = 0; W < NT; ++W) {
    const char* pa = lds + (W & 1) * 65536 + aRow;
    const char* pb = lds + (W & 1) * 65536 + 32768 + bRow;
    i32x4 af[2][4], bf[2][4];   // af reused for m23 at p2

    // ===== phase 0: read A m0-1 (8) + B n0 (4) | barrier | MFMA m01 x n0
#pragma unroll
    for (int m = 0; m < 2; ++m)
#pragma unroll
      for (int ks = 0; ks < 4; ++ks)
        af[m][ks] = *(const i32x4*)(pa + m * 32 * BKB + csk[ks]);
#pragma unroll
    for (int ks = 0; ks < 4; ++ks)
      bf[0][ks] = *(const i32x4*)(pb + csk[ks]);
    __builtin_amdgcn_s_barrier();
    asm volatile("s_waitcnt lgkmcnt(0)" ::: "memory");
    __builtin_amdgcn_sched_barrier(0);
    __builtin_amdgcn_s_setprio(1);
#pragma unroll
    for (int m = 0; m < 2; ++m)
#pragma unroll
      for (int ks = 0; ks < 4; ++ks)
        acc[m][0] = MFMA32(af[m][ks], bf[0][ks], acc[m][0]);
    __builtin_amdgcn_s_setprio(0);

    // ===== phase 1: read B n1 (4) | barrier | MFMA m01 x n1
#pragma unroll
    for (int ks = 0; ks < 4; ++ks)
      bf[1][ks] = *(const i32x4*)(pb + 32 * BKB + csk[ks]);
    __builtin_amdgcn_s_barrier();
    asm volatile("s_waitcnt lgkmcnt(0)" ::: "memory");
    __builtin_amdgcn_sched_barrier(0);
    __builtin_amdgcn_s_setprio(1);
#pragma unroll
    for (int m = 0; m < 2; ++m)
#pragma unroll
      for (int ks = 0; ks < 4; ++ks)
        acc[m][1] = MFMA32(af[m][ks], bf[1][ks], acc[m][1]);
    __builtin_amdgcn_s_setprio(0);

    // ===== phase 2: read A m2-3 (8); stage B(W+2) | barrier | MFMA m23 x n0
#pragma unroll
    for (int m = 0; m < 2; ++m)
#pragma unroll
      for (int ks = 0; ks < 4; ++ks)
        af[m][ks] = *(const i32x4*)(pa + (m + 2) * 32 * BKB + csk[ks]);
    if (W + 2 < NT) { STAGE(0, 0, W + 2); STAGE(0, 1, W + 2); }
    __builtin_amdgcn_s_barrier();
    asm volatile("s_waitcnt lgkmcnt(0)" ::: "memory");
    __builtin_amdgcn_sched_barrier(0);
    __builtin_amdgcn_s_setprio(1);
#pragma unroll
    for (int m = 0; m < 2; ++m)
#pragma unroll
      for (int ks = 0; ks < 4; ++ks)
        acc[m + 2][0] = MFMA32(af[m][ks], bf[0][ks], acc[m + 2][0]);
    __builtin_amdgcn_s_setprio(0);

    // ===== phase 3: stage A(W+2); counted vmcnt | barrier | MFMA m23 x n1
    if (W + 2 < NT) { STAGE(1, 0, W + 2); STAGE(1, 1, W + 2); }
    if (W < NT - 2) { asm volatile("s_waitcnt vmcnt(8)" ::: "memory"); }
    else            { asm volatile("s_waitcnt vmcnt(0)" ::: "memory"); }
    __builtin_amdgcn_s_barrier();
    __builtin_amdgcn_sched_barrier(0);
    __builtin_amdgcn_s_setprio(1);
#pragma unroll
    for (int m = 0; m < 2; ++m)
#pragma unroll
      for (int ks = 0; ks < 4; ++ks)
        acc[m + 2][1] = MFMA32(af[m][ks], bf[1][ks], acc[m + 2][1]);
    __builtin_amdgcn_s_setprio(0);
  }

  // ---- epilogue: z = acc*sc[n] + corr[n]; activation; store
  // C/D layout (32x32): col = lane&31, row = (reg&3) + 8*(reg>>2) + 4*(lane>>5)
#pragma unroll
  for (int n = 0; n < 2; ++n) {
    const int col = bn0 + wc * 64 + n * 32 + fr;
    const float cr = corr[col];
    const float s  = sc[col];
#pragma unroll
    for (int mi = 0; mi < 4; ++mi) {
      const int rbase = bm0 + wr * 128 + mi * 32 + 4 * kg;
#pragma unroll
      for (int r = 0; r < 16; ++r) {
        const int row = rbase + (r & 3) + 8 * (r >> 2);
        float z = (float)acc[mi][n][r] * s + cr;
        float e = __expf((z - 0.183f) * 48.2f);
        C[(size_t)row * N_DIM + col] = 1.096f - 1.924f * __builtin_amdgcn_rcpf(1.0f + e);
      }
    }
  }
#undef STAGE
#undef MFMA32
}

// ---------------------------------------------------------------------------
extern "C" void kernel_launch(void* const* d_in, const int* in_sizes, int n_in,
                              void* d_out, int out_size, void* d_ws, size_t ws_size,
                              hipStream_t stream) {
  (void)in_sizes; (void)n_in; (void)out_size; (void)ws_size;
  const float* a_prev = (const float*)d_in[0];
  const float* theta  = (const float*)d_in[1];
  const float* aging  = (const float*)d_in[2];
  float* out = (float*)d_out;

  char* ws = (char*)d_ws;
  int8_t* Ap = (int8_t*)ws;                                        // 67.1 MB
  int8_t* Bp = (int8_t*)(ws + (size_t)M_DIM * K_DIM);              // 33.6 MB
  float* corr = (float*)(ws + (size_t)M_DIM * K_DIM + (size_t)N_DIM * K_DIM);
  float* sc   = corr + N_DIM;

  prep_A<<<(M_DIM * K_IN / 4) / 256, 256, 0, stream>>>(a_prev, Ap);
  prep_B<<<N_DIM, 256, 0, stream>>>(theta, aging, Bp, corr, sc);

  (void)hipFuncSetAttribute((const void*)gemm_fused,
                            hipFuncAttributeMaxDynamicSharedMemorySize, 131072);
  gemm_fused<<<dim3((M_DIM / BM) * (N_DIM / BN)), dim3(512), 131072, stream>>>(Ap, Bp, corr, sc, out);
}

// Round 9
// 297.979 us; speedup vs baseline: 6.9872x; 1.0271x over previous
//
#include <hip/hip_runtime.h>
#include <hip/hip_bf16.h>
#include <stdint.h>

// Problem dims (fixed by the reference setup_inputs):
//   a_previous [8192, 4096] f32, theta [4096, 4098] f32, aging [4096, 4098] f32
//   out [8192, 4096] f32
#define M_DIM 8192
#define N_DIM 4096
#define K_IN  4096          // n_in
#define NC    (K_IN + 2)    // 4098 theta/aging columns
#define K_DIM (2 * K_IN)    // GEMM K: [a | inv(a)] concatenated, i8 elems (= bytes)

#define BM 256
#define BN 256
#define BKB 128             // K-bytes per tile (i8) -> 128 B rows
#define NT (K_DIM / BKB)    // 64 K-tiles

typedef __attribute__((ext_vector_type(4))) int i32x4;    // 16B A/B fragment
typedef __attribute__((ext_vector_type(16))) int i32x16;  // 32x32 acc

__device__ __forceinline__ float fast_tanh(float y) {
  float e = __expf(2.0f * y);
  return 1.0f - 2.0f * __builtin_amdgcn_rcpf(1.0f + e);
}

__device__ __forceinline__ int q8(float x) {   // round-to-nearest, fits i8 by range
  return (int)__builtin_rintf(x);
}

// ---------------------------------------------------------------------------
// prep_A: A' = [i8(a*127) | i8(inv(a)*127)], shape [8192][8192] i8
// ---------------------------------------------------------------------------
__global__ __launch_bounds__(256) void prep_A(const float* __restrict__ a,
                                              int8_t* __restrict__ Ap) {
  int idx = blockIdx.x * 256 + threadIdx.x;       // one float4 per thread
  int j  = idx >> 10;
  int k4 = (idx & 1023) << 2;
  float4 v = reinterpret_cast<const float4*>(a)[idx];
  float xs[4] = {v.x, v.y, v.z, v.w};
  int lw = 0, rw = 0;
#pragma unroll
  for (int t = 0; t < 4; ++t) {
    float x = xs[t];
    int ql = q8(x * 127.0f);
    float inv = 0.104f - 0.899f * fast_tanh((x + 0.056f) * 3.858f);
    int qr = q8(inv * 127.0f);
    lw |= (ql & 255) << (8 * t);
    rw |= (qr & 255) << (8 * t);
  }
  size_t base = (size_t)j * K_DIM + k4;
  *reinterpret_cast<int*>(Ap + base)        = lw;   // a half
  *reinterpret_cast<int*>(Ap + base + K_IN) = rw;   // inv(a) half
}

// ---------------------------------------------------------------------------
// prep_B: th = st(theta*aging); W = |th|/rowsum; per-row q8 with scale
// 127/max|th_ingemm|; B' = [qWp | qWn] i8; corr[i] f32 exact; sc[i] dequant.
// ---------------------------------------------------------------------------
__global__ __launch_bounds__(256) void prep_B(const float* __restrict__ theta,
                                              const float* __restrict__ aging,
                                              int8_t* __restrict__ Bp,
                                              float* __restrict__ corr,
                                              float* __restrict__ sc) {
  __shared__ float th_s[NC];
  __shared__ float red_s[256];
  __shared__ float red_m[256];
  int i = blockIdx.x;
  int tid = threadIdx.x;
  const float* tr = theta + (size_t)i * NC;
  const float* ar = aging + (size_t)i * NC;
  float psum = 0.f, pmax = 0.f;
  for (int k = tid; k < NC; k += 256) {
    float th = tr[k] * ar[k];
    if (fabsf(th) < 0.01f) th = 0.f;
    th_s[k] = th;
    psum += fabsf(th);
    if (k < K_IN) pmax = fmaxf(pmax, fabsf(th));
  }
  red_s[tid] = psum;
  red_m[tid] = pmax;
  __syncthreads();
  for (int s = 128; s > 0; s >>= 1) {
    if (tid < s) {
      red_s[tid] += red_s[tid + s];
      red_m[tid] = fmaxf(red_m[tid], red_m[tid + s]);
    }
    __syncthreads();
  }
  float inv_sum = 1.0f / red_s[0];
  float maxabs  = red_m[0];
  float qs = 127.0f / maxabs;
  int8_t* out = Bp + (size_t)i * K_DIM;
  for (int k0 = tid * 4; k0 < K_IN; k0 += 1024) {
    int pw = 0, nw = 0;
#pragma unroll
    for (int t = 0; t < 4; ++t) {
      float th = th_s[k0 + t];
      int q = q8(fabsf(th) * qs);
      if (th >= 0.f) pw |= (q & 255) << (8 * t);
      else           nw |= (q & 255) << (8 * t);
    }
    *reinterpret_cast<int*>(out + k0)         = pw;   // Wp (pairs with a)
    *reinterpret_cast<int*>(out + K_IN + k0)  = nw;   // Wn (pairs with inv(a))
  }
  if (tid == 0) {
    float th1 = th_s[K_IN];
    float th2 = th_s[K_IN + 1];
    float w1 = fabsf(th1) * inv_sum;
    float w2 = fabsf(th2) * inv_sum;
    float inv1 = 0.104f - 0.899f * fast_tanh((1.0f + 0.056f) * 3.858f);
    float inv0 = 0.104f - 0.899f * fast_tanh((0.0f + 0.056f) * 3.858f);
    float c = (th1 >= 0.f) ? w1 : w1 * inv1;
    c += (th2 >= 0.f) ? 0.0f : w2 * inv0;
    corr[i] = c;
    sc[i] = maxabs * inv_sum * (1.0f / 16129.0f);   // 1/(127*127)
  }
}

// ---------------------------------------------------------------------------
// gemm_fused (i8, 32x32x32): R8 structure with the swizzle re-derived for the
// 32-row fragment pattern. R8's flip=(row&7)<<4 left rows {r,r+8,r+16,r+24}
// (same row&7, same kg) on the SAME 16B slot -> 4-way bank groups -> 2.5e7
// conflict cycles. New flip folds row bits 3-4: slot ^= (row&7) ^ ((row>>3)&3)
// -> under consecutive-8 / stride-8 / 16-lane groupings every slot has <=2
// lanes (2-way = free, m136). Involution pair (rule 21): same XOR applied to
// the staging GLOBAL source slot; LDS dest stays linear (glds requirement).
// Everything else identical to R8 (absmax-0-verified schedule & epilogue).
// ---------------------------------------------------------------------------
__global__ __launch_bounds__(512, 2) void gemm_fused(const int8_t* __restrict__ A,
                                                     const int8_t* __restrict__ B,
                                                     const float* __restrict__ corr,
                                                     const float* __restrict__ sc,
                                                     float* __restrict__ C) {
  extern __shared__ char lds[];   // 131072 B
  const int tid  = threadIdx.x;
  const int lane = tid & 63;
  const int wid  = tid >> 6;     // 0..7
  const int wr   = wid >> 2;     // 0..1  -> M offset wr*128
  const int wc   = wid & 3;      // 0..3  -> N offset wc*64
  const int fr   = lane & 31;    // fragment row/col (32-row tiles)
  const int kg   = lane >> 5;    // k-group 0/1 (16B each)

  // T1: XCD-aware swizzle; nwg = 512, divisible by 8 -> bijective
  const int bid = (int)blockIdx.x;
  const int sw  = (bid & 7) * 64 + (bid >> 3);
  const int bm0 = (sw >> 4) * BM;     // 32 M-blocks
  const int bn0 = (sw & 15) * BN;     // 16 N-blocks

  // staging: linear LDS dest (glds); GLOBAL source slot pre-swizzled with the
  // inverse (= same, involution) of the read XOR. Thread t writes row t>>3,
  // physical slot t&7; data for that cell is logical slot (t&7)^(r&7)^((r>>3)&3)
  const int colsw = (((tid & 7) ^ ((tid >> 3) & 7) ^ ((tid >> 6) & 3)) << 4);
  const int8_t* gA = A + (size_t)(bm0 + (tid >> 3)) * K_DIM + colsw;
  const int8_t* gB = B + (size_t)(bn0 + (tid >> 3)) * K_DIM + colsw;
  const int dst_t = tid * 16;

  // read-side swizzled fragment byte offsets (within a 128B row)
  const int flip = (((fr & 7) ^ ((fr >> 3) & 3)) << 4);
  int csk[4];
#pragma unroll
  for (int ks = 0; ks < 4; ++ks) csk[ks] = (ks * 32 + kg * 16) ^ flip;
  const int aRow = (wr * 128 + fr) * BKB;              // byte offset of frag row
  const int bRow = (wc * 64 + fr) * BKB;

  i32x16 acc[4][2] = {};   // [m-tile][n-tile]

#define STAGE(ISA, H, T) do {                                                        \
    const int8_t* _g = (ISA) ? gA : gB;                                              \
    const size_t _go = (size_t)((H) * 128) * K_DIM + (size_t)(T) * BKB;              \
    char* _l = lds + (((T) & 1) * 65536) + ((ISA) ? 0 : 32768) + (H) * 16384 + dst_t; \
    __builtin_amdgcn_global_load_lds(                                                \
        (const __attribute__((address_space(1))) unsigned int*)(_g + _go),           \
        (__attribute__((address_space(3))) unsigned int*)_l, 16, 0, 0);              \
    __builtin_amdgcn_global_load_lds(                                                \
        (const __attribute__((address_space(1))) unsigned int*)(_g + _go + (size_t)64 * K_DIM), \
        (__attribute__((address_space(3))) unsigned int*)(_l + 8192), 16, 0, 0);     \
  } while (0)

#define MFMA32(a, b, c) __builtin_amdgcn_mfma_i32_32x32x32_i8((a), (b), (c), 0, 0, 0)

  // ---- prologue: tile0 + tile1 fully staged (16 loads); wait tile0 (8 left)
  STAGE(0, 0, 0); STAGE(0, 1, 0); STAGE(1, 0, 0); STAGE(1, 1, 0);
  STAGE(0, 0, 1); STAGE(0, 1, 1); STAGE(1, 0, 1); STAGE(1, 1, 1);
  asm volatile("s_waitcnt vmcnt(8)" ::: "memory");
  __builtin_amdgcn_s_barrier();

#pragma unroll 2
  for (int W = 0; W < NT; ++W) {
    const char* pa = lds + (W & 1) * 65536 + aRow;
    const char* pb = lds + (W & 1) * 65536 + 32768 + bRow;
    i32x4 af[2][4], bf[2][4];   // af reused for m23 at p2

    // ===== phase 0: read A m0-1 (8) + B n0 (4) | barrier | MFMA m01 x n0
#pragma unroll
    for (int m = 0; m < 2; ++m)
#pragma unroll
      for (int ks = 0; ks < 4; ++ks)
        af[m][ks] = *(const i32x4*)(pa + m * 32 * BKB + csk[ks]);
#pragma unroll
    for (int ks = 0; ks < 4; ++ks)
      bf[0][ks] = *(const i32x4*)(pb + csk[ks]);
    __builtin_amdgcn_s_barrier();
    asm volatile("s_waitcnt lgkmcnt(0)" ::: "memory");
    __builtin_amdgcn_sched_barrier(0);
    __builtin_amdgcn_s_setprio(1);
#pragma unroll
    for (int m = 0; m < 2; ++m)
#pragma unroll
      for (int ks = 0; ks < 4; ++ks)
        acc[m][0] = MFMA32(af[m][ks], bf[0][ks], acc[m][0]);
    __builtin_amdgcn_s_setprio(0);

    // ===== phase 1: read B n1 (4) | barrier | MFMA m01 x n1
#pragma unroll
    for (int ks = 0; ks < 4; ++ks)
      bf[1][ks] = *(const i32x4*)(pb + 32 * BKB + csk[ks]);
    __builtin_amdgcn_s_barrier();
    asm volatile("s_waitcnt lgkmcnt(0)" ::: "memory");
    __builtin_amdgcn_sched_barrier(0);
    __builtin_amdgcn_s_setprio(1);
#pragma unroll
    for (int m = 0; m < 2; ++m)
#pragma unroll
      for (int ks = 0; ks < 4; ++ks)
        acc[m][1] = MFMA32(af[m][ks], bf[1][ks], acc[m][1]);
    __builtin_amdgcn_s_setprio(0);

    // ===== phase 2: read A m2-3 (8); stage B(W+2) | barrier | MFMA m23 x n0
#pragma unroll
    for (int m = 0; m < 2; ++m)
#pragma unroll
      for (int ks = 0; ks < 4; ++ks)
        af[m][ks] = *(const i32x4*)(pa + (m + 2) * 32 * BKB + csk[ks]);
    if (W + 2 < NT) { STAGE(0, 0, W + 2); STAGE(0, 1, W + 2); }
    __builtin_amdgcn_s_barrier();
    asm volatile("s_waitcnt lgkmcnt(0)" ::: "memory");
    __builtin_amdgcn_sched_barrier(0);
    __builtin_amdgcn_s_setprio(1);
#pragma unroll
    for (int m = 0; m < 2; ++m)
#pragma unroll
      for (int ks = 0; ks < 4; ++ks)
        acc[m + 2][0] = MFMA32(af[m][ks], bf[0][ks], acc[m + 2][0]);
    __builtin_amdgcn_s_setprio(0);

    // ===== phase 3: stage A(W+2); counted vmcnt | barrier | MFMA m23 x n1
    if (W + 2 < NT) { STAGE(1, 0, W + 2); STAGE(1, 1, W + 2); }
    if (W < NT - 2) { asm volatile("s_waitcnt vmcnt(8)" ::: "memory"); }
    else            { asm volatile("s_waitcnt vmcnt(0)" ::: "memory"); }
    __builtin_amdgcn_s_barrier();
    __builtin_amdgcn_sched_barrier(0);
    __builtin_amdgcn_s_setprio(1);
#pragma unroll
    for (int m = 0; m < 2; ++m)
#pragma unroll
      for (int ks = 0; ks < 4; ++ks)
        acc[m + 2][1] = MFMA32(af[m][ks], bf[1][ks], acc[m + 2][1]);
    __builtin_amdgcn_s_setprio(0);
  }

  // ---- epilogue: z = acc*sc[n] + corr[n]; activation; store
  // C/D layout (32x32): col = lane&31, row = (reg&3) + 8*(reg>>2) + 4*(lane>>5)
#pragma unroll
  for (int n = 0; n < 2; ++n) {
    const int col = bn0 + wc * 64 + n * 32 + fr;
    const float cr = corr[col];
    const float s  = sc[col];
#pragma unroll
    for (int mi = 0; mi < 4; ++mi) {
      const int rbase = bm0 + wr * 128 + mi * 32 + 4 * kg;
#pragma unroll
      for (int r = 0; r < 16; ++r) {
        const int row = rbase + (r & 3) + 8 * (r >> 2);
        float z = (float)acc[mi][n][r] * s + cr;
        float e = __expf((z - 0.183f) * 48.2f);
        C[(size_t)row * N_DIM + col] = 1.096f - 1.924f * __builtin_amdgcn_rcpf(1.0f + e);
      }
    }
  }
#undef STAGE
#undef MFMA32
}

// ---------------------------------------------------------------------------
extern "C" void kernel_launch(void* const* d_in, const int* in_sizes, int n_in,
                              void* d_out, int out_size, void* d_ws, size_t ws_size,
                              hipStream_t stream) {
  (void)in_sizes; (void)n_in; (void)out_size; (void)ws_size;
  const float* a_prev = (const float*)d_in[0];
  const float* theta  = (const float*)d_in[1];
  const float* aging  = (const float*)d_in[2];
  float* out = (float*)d_out;

  char* ws = (char*)d_ws;
  int8_t* Ap = (int8_t*)ws;                                        // 67.1 MB
  int8_t* Bp = (int8_t*)(ws + (size_t)M_DIM * K_DIM);              // 33.6 MB
  float* corr = (float*)(ws + (size_t)M_DIM * K_DIM + (size_t)N_DIM * K_DIM);
  float* sc   = corr + N_DIM;

  prep_A<<<(M_DIM * K_IN / 4) / 256, 256, 0, stream>>>(a_prev, Ap);
  prep_B<<<N_DIM, 256, 0, stream>>>(theta, aging, Bp, corr, sc);

  (void)hipFuncSetAttribute((const void*)gemm_fused,
                            hipFuncAttributeMaxDynamicSharedMemorySize, 131072);
  gemm_fused<<<dim3((M_DIM / BM) * (N_DIM / BN)), dim3(512), 131072, stream>>>(Ap, Bp, corr, sc, out);
}